// Round 3
// baseline (5260.383 us; speedup 1.0000x reference)
//
#include <hip/hip_runtime.h>

#define SEQL 1024
#define BATCHN 128
#define UNITS 256
#define INDIM 128
#define G3 768   // r|u|h gate columns

typedef __attribute__((ext_vector_type(8))) short short8;
typedef __attribute__((ext_vector_type(4))) short short4v;
typedef __attribute__((ext_vector_type(4))) float floatx4;

#define NL2E  -1.4426950408889634f   // -log2(e): r,u gate scale
#define PL2E2  2.8853900817779268f   //  2*log2(e): h gate scale

#define HSTRIDE 272                  // compact h row stride (shorts), breaks bank alias

__device__ __forceinline__ short f2bf(float f) {
  unsigned u = __float_as_uint(f);
  u += 0x7fff + ((u >> 16) & 1);   // round-to-nearest-even
  return (short)(u >> 16);
}
__device__ __forceinline__ float bf2f(unsigned short s) {
  return __uint_as_float(((unsigned)s) << 16);
}
__device__ __forceinline__ float fexp2(float x) {
#if __has_builtin(__builtin_amdgcn_exp2f)
  return __builtin_amdgcn_exp2f(x);
#else
  return __expf(0.6931471805599453f * x);
#endif
}
__device__ __forceinline__ float frcp(float x) {
#if __has_builtin(__builtin_amdgcn_rcpf)
  return __builtin_amdgcn_rcpf(x);
#else
  return 1.f / x;
#endif
}

// LDS-only barrier: orders ds ops without draining vmcnt.
#define LDS_BARRIER() do {                                   \
    asm volatile("s_waitcnt lgkmcnt(0)" ::: "memory");       \
    __builtin_amdgcn_s_barrier();                            \
    asm volatile("" ::: "memory");                           \
  } while (0)

// Opaque per-iteration pin: a volatile asm INSIDE the t-loop cannot be
// hoisted, so the value must be live in VGPRs at every iteration —
// rematerializing the load per use is no longer legal. (A pre-loop pin
// was proven insufficient: VGPR_Count stayed 120, weights re-streamed
// from L2 every step.)
#define PIN8(x) asm volatile("" : "+v"(x))

// ---------------------------------------------------------------------------
// Kernel A: combined input weight WcB (384x768 bf16, B-frag layout) and
// recurrent weight WhB (256x768 bf16, B-frag layout), gate-scaled so the
// epilogues are pure exp2/rcp:  r,u cols x(-log2e);  h cols x(+2 log2e).
// Frag layout: W[k][n] at ((n*KKmax + kk)*4 + q)*8 + j, kk=k>>5,q=(k>>3)&3,j=k&7.
// ---------------------------------------------------------------------------
__global__ void prep_kernel(const float* __restrict__ iw,   // (128,1792)
                            const float* __restrict__ hw,   // (256,768)
                            short* __restrict__ WcB, short* __restrict__ WhB) {
  int idx = blockIdx.x * 256 + threadIdx.x;
  const int WCN = 384 * G3;
  if (idx < WCN) {
    int k = idx / G3, n = idx % G3;
    int i = k & 127, blkk = k >> 7;      // 0:x_t 1:x_{t-1} 2:x_{t-2}
    int gsel = n >> 8, c = n & 255;      // 0:r 1:u 2:h
    const float* row = iw + (size_t)i * 1792;
    float v;
    if (blkk == 0) {
      v = (gsel == 0) ? row[c] + row[768 + c] + row[1280 + c]
        : (gsel == 1) ? row[256 + c] + row[1024 + c] + row[1536 + c]
                      : row[512 + c];
    } else if (blkk == 1) {
      v = (gsel == 0) ? -(row[768 + c] + 2.f * row[1280 + c])
        : (gsel == 1) ? -(row[1024 + c] + 2.f * row[1536 + c])
                      : 0.f;
    } else {
      v = (gsel == 0) ? row[1280 + c]
        : (gsel == 1) ? row[1536 + c]
                      : 0.f;
    }
    v *= (gsel == 2) ? PL2E2 : NL2E;
    int kk = k >> 5, q = (k >> 3) & 3, j = k & 7;
    WcB[(((n * 12 + kk) * 4 + q) * 8) + j] = f2bf(v);
  } else {
    idx -= WCN;
    if (idx < 256 * G3) {
      int k = idx / G3, n = idx % G3;
      float v = hw[(size_t)k * G3 + n] * ((n >> 8) == 2 ? PL2E2 : NL2E);
      int kk = k >> 5, q = (k >> 3) & 3, j = k & 7;
      WhB[(((n * 8 + kk) * 4 + q) * 8) + j] = f2bf(v);
    }
  }
}

// ---------------------------------------------------------------------------
// Kernel B: input projection (M=16 batch rows per block). Output stored as
// per-(rnn_wg, t) slabs of 3x512 dwords: slab[g*512 + tid] = pack(nt0, nt1)
// where tid = wv*64 + q*16 + ln16 is the CONSUMING rnn thread; rnn_wg owns
// 4 batch rows (wg = mt*4 + q_proj, row-in-wg = reg r).
// ---------------------------------------------------------------------------
__global__ __launch_bounds__(256) void proj_kernel(const float* __restrict__ x,
                                                   const short* __restrict__ WcB,
                                                   const float* __restrict__ bias,
                                                   unsigned* __restrict__ pre2) {
  __shared__ short xF[12 * 64 * 8];     // A-frag: [kk][lane][8] bf16, 12KB
  const int tid = threadIdx.x;
  const int t = blockIdx.x >> 3;
  const int mt = blockIdx.x & 7;        // 16-row batch group

#pragma unroll
  for (int it = 0; it < 6; ++it) {
    int rr = it * 8 + (tid >> 5);       // 0..47 = dt*16 + bb
    int dt = rr >> 4, bb = rr & 15;
    int lane32 = tid & 31, c = lane32 * 4;
    floatx4 v = {0.f, 0.f, 0.f, 0.f};
    if (t >= dt)
      v = *(const floatx4*)(x + ((size_t)(mt * 16 + bb) * SEQL + (t - dt)) * INDIM + c);
    int kk = dt * 4 + (c >> 5), qq = (c >> 3) & 3, j0 = c & 7;
    short4v pk;
#pragma unroll
    for (int j = 0; j < 4; ++j) pk[j] = f2bf(v[j]);
    *(short4v*)&xF[((kk * 64 + qq * 16 + bb) * 8) + j0] = pk;
  }
  __syncthreads();

  const int wvp = tid >> 6, lane = tid & 63, ln16 = lane & 15;
  const int qp = lane >> 4;

  short8 aF[12];
#pragma unroll
  for (int kk = 0; kk < 12; ++kk) aF[kk] = *(const short8*)&xF[(kk * 64 + lane) * 8];

  // this lane's C-rows are batch rows mt*16 + qp*4 + r  ->  rnn wg = mt*4+qp
  unsigned* slab = pre2 + (size_t)((mt * 4 + qp) * SEQL + t) * 1536;

#pragma unroll
  for (int ig = 0; ig < 3; ++ig) {
    const int ngrp = wvp * 3 + ig;                 // 0..11 -> 64-col group
    const float sc = (ngrp >= 8) ? PL2E2 : NL2E;
    floatx4 acc[4];
#pragma unroll
    for (int nt = 0; nt < 4; ++nt) {
      float bv = bias[ngrp * 64 + nt * 16 + ln16] * sc;
#pragma unroll
      for (int r = 0; r < 4; ++r) acc[nt][r] = bv;
    }
#pragma unroll
    for (int kk = 0; kk < 12; ++kk) {
#pragma unroll
      for (int nt = 0; nt < 4; ++nt) {
        int n = ngrp * 64 + nt * 16 + ln16;
        short8 w = *(const short8*)(WcB + (((size_t)(n * 12 + kk) * 4 + qp) * 8));
        acc[nt] = __builtin_amdgcn_mfma_f32_16x16x32_bf16(aF[kk], w, acc[nt], 0, 0, 0);
      }
    }
    const int g = ngrp >> 2;                       // gate 0:r 1:u 2:h
#pragma unroll
    for (int p = 0; p < 2; ++p) {                  // nt_p pair (2p, 2p+1)
      int wv = (ngrp & 3) * 2 + p;                 // consuming rnn wave
#pragma unroll
      for (int r = 0; r < 4; ++r) {
        unsigned lo = (unsigned)(unsigned short)f2bf(acc[2 * p][r]);
        unsigned hi = (unsigned)(unsigned short)f2bf(acc[2 * p + 1][r]);
        slab[g * 512 + wv * 64 + r * 16 + ln16] = lo | (hi << 16);
      }
    }
  }
}

// ---------------------------------------------------------------------------
// Kernel C: persistent recurrence. 32 WGs x 512 threads; 4 batch rows per WG.
// Restructured phases:
//   phase A: R = h@Whr only (16 MFMA/wave), aF (h frags) RETAINED in regs.
//   bar1.
//   phase B: U = aF@Whu from registers (independent of barrier -> hides the
//            post-barrier rFc LDS latency and wH load latency), then
//            H = rFc@Whh with wH streamed per-kk from L2.
//   epilogue B writes hFc (safe: nothing reads hFc after bar1). bar2.
// wR,wU pinned resident per-iteration (128 VGPRs); wH streamed.
// ---------------------------------------------------------------------------
__global__ __launch_bounds__(512, 2) void rnn_kernel(const unsigned* __restrict__ pre2,
                                                     const short* __restrict__ WhB,
                                                     float* __restrict__ out) {
  __shared__ __align__(16) short hFc[4 * HSTRIDE];   // h,  rows 0..3 compact
  __shared__ __align__(16) short rFc[4 * HSTRIDE];   // r*h

  const int tid = threadIdx.x;
  const int wv = tid >> 6, lane = tid & 63, ln16 = lane & 15, q = lane >> 4;
  const int row4 = lane & 3;            // A-frag source row (m & 3)
  const int wg = blockIdx.x;

  // persistent weight fragments: this wave's 32 cols of R and U gates
  short8 wR[2][8], wU[2][8];
#pragma unroll
  for (int nt = 0; nt < 2; ++nt) {
    int nr = wv * 32 + nt * 16 + ln16;
#pragma unroll
    for (int kk = 0; kk < 8; ++kk) {
      wR[nt][kk] = *(const short8*)(WhB + (((size_t)(nr * 8 + kk) * 4 + q) * 8));
      wU[nt][kk] = *(const short8*)(WhB + (((size_t)((256 + nr) * 8 + kk) * 4 + q) * 8));
    }
  }
  // H-gate weight base pointers (streamed per step; frag kk at +kk*32 shorts)
  const short* wHb0 = WhB + ((size_t)(512 + wv * 32 + 0 * 16 + ln16) * 256) + q * 8;
  const short* wHb1 = WhB + ((size_t)(512 + wv * 32 + 1 * 16 + ln16) * 256) + q * 8;

  for (int i = tid; i < 4 * HSTRIDE; i += 512) { hFc[i] = 0; rFc[i] = 0; }

  const floatx4 z4 = {0.f, 0.f, 0.f, 0.f};
  float hq[2] = {0.f, 0.f};             // h(row=q, col = wv*32 + nt*16 + ln16)

  const unsigned* slab0 = pre2 + (size_t)wg * SEQL * 1536;
  unsigned cur0 = slab0[0 * 512 + tid];
  unsigned cur1 = slab0[1 * 512 + tid];
  unsigned cur2 = slab0[2 * 512 + tid];

  float* outBase = out + ((size_t)(wg * 4 + q) * SEQL) * UNITS + wv * 32 + ln16;
  const int aoff = row4 * HSTRIDE + q * 8;       // + kk*32 per step
  const int woff = q * HSTRIDE + wv * 32 + ln16; // + nt*16

  __syncthreads();

  for (int t = 0; t < SEQL; ++t) {
    // pin R,U weights resident THIS iteration (volatile: not hoistable)
#pragma unroll
    for (int nt = 0; nt < 2; ++nt)
#pragma unroll
      for (int kk = 0; kk < 8; ++kk) { PIN8(wR[nt][kk]); PIN8(wU[nt][kk]); }

    const unsigned* nslab = slab0 + (size_t)(t < SEQL - 1 ? t + 1 : t) * 1536;
    unsigned nxt0 = nslab[0 * 512 + tid];
    unsigned nxt1 = nslab[1 * 512 + tid];
    unsigned nxt2 = nslab[2 * 512 + tid];

    // ---- phase A: R pre-acts only; retain h A-frags in aF ----
    short8 aF[8];
    floatx4 accR[2];
    aF[0] = *(const short8*)&hFc[aoff];
    accR[0] = __builtin_amdgcn_mfma_f32_16x16x32_bf16(aF[0], wR[0][0], z4, 0, 0, 0);
    accR[1] = __builtin_amdgcn_mfma_f32_16x16x32_bf16(aF[0], wR[1][0], z4, 0, 0, 0);
#pragma unroll
    for (int kk = 1; kk < 8; ++kk) {
      aF[kk] = *(const short8*)&hFc[aoff + kk * 32];
      accR[0] = __builtin_amdgcn_mfma_f32_16x16x32_bf16(aF[kk], wR[0][kk], accR[0], 0, 0, 0);
      accR[1] = __builtin_amdgcn_mfma_f32_16x16x32_bf16(aF[kk], wR[1][kk], accR[1], 0, 0, 0);
    }
    // r epilogue: write r*h fragments
#pragma unroll
    for (int nt = 0; nt < 2; ++nt) {
      float vR = (q == 0) ? accR[nt][0] : (q == 1) ? accR[nt][1]
               : (q == 2) ? accR[nt][2] : accR[nt][3];
      float pR = bf2f((unsigned short)(nt ? (cur0 >> 16) : (cur0 & 0xffff)));
      float rg = frcp(1.f + fexp2(vR + pR));
      rFc[woff + nt * 16] = f2bf(rg * hq[nt]);
    }
    LDS_BARRIER();

    // ---- phase B: U from retained regs (no LDS dep), then H from rFc ----
    floatx4 accU[2];
    accU[0] = __builtin_amdgcn_mfma_f32_16x16x32_bf16(aF[0], wU[0][0], z4, 0, 0, 0);
    accU[1] = __builtin_amdgcn_mfma_f32_16x16x32_bf16(aF[0], wU[1][0], z4, 0, 0, 0);
#pragma unroll
    for (int kk = 1; kk < 8; ++kk) {
      accU[0] = __builtin_amdgcn_mfma_f32_16x16x32_bf16(aF[kk], wU[0][kk], accU[0], 0, 0, 0);
      accU[1] = __builtin_amdgcn_mfma_f32_16x16x32_bf16(aF[kk], wU[1][kk], accU[1], 0, 0, 0);
    }
    floatx4 accH[2];
    {
      const short8 aH0 = *(const short8*)&rFc[aoff];
      const short8 wh0 = *(const short8*)(wHb0);
      const short8 wh1 = *(const short8*)(wHb1);
      accH[0] = __builtin_amdgcn_mfma_f32_16x16x32_bf16(aH0, wh0, z4, 0, 0, 0);
      accH[1] = __builtin_amdgcn_mfma_f32_16x16x32_bf16(aH0, wh1, z4, 0, 0, 0);
    }
#pragma unroll
    for (int kk = 1; kk < 8; ++kk) {
      const short8 aH = *(const short8*)&rFc[aoff + kk * 32];
      const short8 wh0 = *(const short8*)(wHb0 + kk * 32);
      const short8 wh1 = *(const short8*)(wHb1 + kk * 32);
      accH[0] = __builtin_amdgcn_mfma_f32_16x16x32_bf16(aH, wh0, accH[0], 0, 0, 0);
      accH[1] = __builtin_amdgcn_mfma_f32_16x16x32_bf16(aH, wh1, accH[1], 0, 0, 0);
    }
    // u, cand, h update
#pragma unroll
    for (int nt = 0; nt < 2; ++nt) {
      float vU = (q == 0) ? accU[nt][0] : (q == 1) ? accU[nt][1]
               : (q == 2) ? accU[nt][2] : accU[nt][3];
      float vH = (q == 0) ? accH[nt][0] : (q == 1) ? accH[nt][1]
               : (q == 2) ? accH[nt][2] : accH[nt][3];
      float pU = bf2f((unsigned short)(nt ? (cur1 >> 16) : (cur1 & 0xffff)));
      float pH = bf2f((unsigned short)(nt ? (cur2 >> 16) : (cur2 & 0xffff)));
      float uqv  = frcp(1.f + fexp2(vU + pU));
      float cand = 1.f - 2.f * frcp(1.f + fexp2(vH + pH));   // tanh (scale folded)
      float hnew = uqv * (hq[nt] - cand) + cand;
      hq[nt] = hnew;
      hFc[woff + nt * 16] = f2bf(hnew);
      outBase[(size_t)t * UNITS + nt * 16] = hnew;
    }
    cur0 = nxt0; cur1 = nxt1; cur2 = nxt2;
    LDS_BARRIER();
  }
}

extern "C" void kernel_launch(void* const* d_in, const int* in_sizes, int n_in,
                              void* d_out, int out_size, void* d_ws, size_t ws_size,
                              hipStream_t stream) {
  const float* x    = (const float*)d_in[0];
  const float* iw   = (const float*)d_in[1];
  const float* hw   = (const float*)d_in[2];
  const float* bias = (const float*)d_in[3];
  // d_in[4] (constant) is [I;0] — folded analytically, unused.
  float* out = (float*)d_out;

  unsigned* pre2 = (unsigned*)d_ws;                    // 32*1024*1536 dwords = 192 MB
  const size_t preDwords = (size_t)32 * SEQL * 1536;
  short* WcB = (short*)(pre2 + preDwords);             // 384*768 bf16
  short* WhB = WcB + (size_t)384 * G3;                 // 256*768 bf16

  prep_kernel<<<1920, 256, 0, stream>>>(iw, hw, WcB, WhB);
  proj_kernel<<<8192, 256, 0, stream>>>(x, WcB, bias, pre2);
  rnn_kernel<<<32, 512, 0, stream>>>(pre2, WhB, out);
}

// Round 4
// 1573.740 us; speedup vs baseline: 3.3426x; 3.3426x over previous
//
#include <hip/hip_runtime.h>

#define SEQL 1024
#define BATCHN 128
#define UNITS 256
#define INDIM 128
#define G3 768   // r|u|h gate columns

typedef __attribute__((ext_vector_type(8))) short short8;
typedef __attribute__((ext_vector_type(4))) short short4v;
typedef __attribute__((ext_vector_type(4))) float floatx4;

#define NL2E  -1.4426950408889634f   // -log2(e): r,u gate scale
#define PL2E2  2.8853900817779268f   //  2*log2(e): h gate scale

#define HSTRIDE 272                  // compact h row stride (shorts), breaks bank alias

__device__ __forceinline__ short f2bf(float f) {
  unsigned u = __float_as_uint(f);
  u += 0x7fff + ((u >> 16) & 1);   // round-to-nearest-even
  return (short)(u >> 16);
}
__device__ __forceinline__ float bf2f(unsigned short s) {
  return __uint_as_float(((unsigned)s) << 16);
}
__device__ __forceinline__ float fexp2(float x) {
#if __has_builtin(__builtin_amdgcn_exp2f)
  return __builtin_amdgcn_exp2f(x);
#else
  return __expf(0.6931471805599453f * x);
#endif
}
__device__ __forceinline__ float frcp(float x) {
#if __has_builtin(__builtin_amdgcn_rcpf)
  return __builtin_amdgcn_rcpf(x);
#else
  return 1.f / x;
#endif
}

// LDS-only barrier: orders ds ops without draining vmcnt.
#define LDS_BARRIER() do {                                   \
    asm volatile("s_waitcnt lgkmcnt(0)" ::: "memory");       \
    __builtin_amdgcn_s_barrier();                            \
    asm volatile("" ::: "memory");                           \
  } while (0)

// Acquire-spin on a producer flag. Acquire semantics invalidate stale L2
// lines each poll, so progress is guaranteed even if a relaxed fast-path
// read saw a stale 0.
__device__ __forceinline__ void acq_spin(const int* p) {
  while (__hip_atomic_load(p, __ATOMIC_ACQUIRE, __HIP_MEMORY_SCOPE_AGENT) == 0)
    __builtin_amdgcn_s_sleep(8);
}

// ---------------------------------------------------------------------------
// Kernel A: weight prep (unchanged math) + zeroing the 8192 producer flags.
// Grid 1952x256 = 294912 (WcB) + 196608 (WhB) + 8192 (flags) exactly.
// ---------------------------------------------------------------------------
__global__ void prep_kernel(const float* __restrict__ iw,   // (128,1792)
                            const float* __restrict__ hw,   // (256,768)
                            short* __restrict__ WcB, short* __restrict__ WhB,
                            int* __restrict__ flags) {
  int idx = blockIdx.x * 256 + threadIdx.x;
  const int WCN = 384 * G3;
  if (idx < WCN) {
    int k = idx / G3, n = idx % G3;
    int i = k & 127, blkk = k >> 7;      // 0:x_t 1:x_{t-1} 2:x_{t-2}
    int gsel = n >> 8, c = n & 255;      // 0:r 1:u 2:h
    const float* row = iw + (size_t)i * 1792;
    float v;
    if (blkk == 0) {
      v = (gsel == 0) ? row[c] + row[768 + c] + row[1280 + c]
        : (gsel == 1) ? row[256 + c] + row[1024 + c] + row[1536 + c]
                      : row[512 + c];
    } else if (blkk == 1) {
      v = (gsel == 0) ? -(row[768 + c] + 2.f * row[1280 + c])
        : (gsel == 1) ? -(row[1024 + c] + 2.f * row[1536 + c])
                      : 0.f;
    } else {
      v = (gsel == 0) ? row[1280 + c]
        : (gsel == 1) ? row[1536 + c]
                      : 0.f;
    }
    v *= (gsel == 2) ? PL2E2 : NL2E;
    int kk = k >> 5, q = (k >> 3) & 3, j = k & 7;
    WcB[(((n * 12 + kk) * 4 + q) * 8) + j] = f2bf(v);
  } else {
    idx -= WCN;
    if (idx < 256 * G3) {
      int k = idx / G3, n = idx % G3;
      float v = hw[(size_t)k * G3 + n] * ((n >> 8) == 2 ? PL2E2 : NL2E);
      int kk = k >> 5, q = (k >> 3) & 3, j = k & 7;
      WhB[(((n * 8 + kk) * 4 + q) * 8) + j] = f2bf(v);
    } else {
      idx -= 256 * G3;
      if (idx < SEQL * 8) flags[idx] = 0;
    }
  }
}

// ---------------------------------------------------------------------------
// Fused kernel: blocks 0..31 = persistent recurrence (consumer), blocks
// 32..4127 = input projection (producer), one proj block per (t-pair, mt),
// t-major so production tracks consumption order. Handoff via flags[t*8+mt]:
// producer: syncthreads (drains stores) -> threadfence (L2 wb, cross-XCD
// visibility) -> release-store flag. Consumer: relaxed flag read pipelined
// one full step ahead (latency hidden), acquire-spin slow path.
// ---------------------------------------------------------------------------
__global__ __launch_bounds__(512, 2) void fused_kernel(
    const float* __restrict__ x, const short* __restrict__ WcB,
    const float* __restrict__ bias, unsigned* __restrict__ pre2,
    const short* __restrict__ WhB, float* __restrict__ out,
    int* __restrict__ flags) {
  __shared__ __align__(16) short smem[12288];   // 24 KB: proj 2x6144, rnn 2176

  if (blockIdx.x >= 32) {
    // =================== proj role: (t-pair, mt) ===================
    const int pidx = blockIdx.x - 32;
    const int tpair = pidx >> 3, mt = pidx & 7;
    const int tid = threadIdx.x;
    const int half = tid >> 8, htid = tid & 255;
    const int t = tpair * 2 + half;
    short* xF = smem + half * 6144;             // [kk][lane][8] bf16 A-frags

#pragma unroll
    for (int it = 0; it < 6; ++it) {
      int rr = it * 8 + (htid >> 5);            // 0..47 = dt*16 + bb
      int dt = rr >> 4, bb = rr & 15;
      int lane32 = htid & 31, c = lane32 * 4;
      floatx4 v = {0.f, 0.f, 0.f, 0.f};
      if (t >= dt)
        v = *(const floatx4*)(x + ((size_t)(mt * 16 + bb) * SEQL + (t - dt)) * INDIM + c);
      int kk = dt * 4 + (c >> 5), qq = (c >> 3) & 3, j0 = c & 7;
      short4v pk;
#pragma unroll
      for (int j = 0; j < 4; ++j) pk[j] = f2bf(v[j]);
      *(short4v*)&xF[((kk * 64 + qq * 16 + bb) * 8) + j0] = pk;
    }
    __syncthreads();

    const int wvp = htid >> 6, lane = htid & 63, ln16 = lane & 15;
    const int qp = lane >> 4;

    short8 aF[12];
#pragma unroll
    for (int kk = 0; kk < 12; ++kk) aF[kk] = *(const short8*)&xF[(kk * 64 + lane) * 8];

    unsigned* slab = pre2 + (size_t)((mt * 4 + qp) * SEQL + t) * 1536;

#pragma unroll
    for (int ig = 0; ig < 3; ++ig) {
      const int ngrp = wvp * 3 + ig;               // 0..11 -> 64-col group
      const float sc = (ngrp >= 8) ? PL2E2 : NL2E;
      floatx4 acc[4];
#pragma unroll
      for (int nt = 0; nt < 4; ++nt) {
        float bv = bias[ngrp * 64 + nt * 16 + ln16] * sc;
#pragma unroll
        for (int r = 0; r < 4; ++r) acc[nt][r] = bv;
      }
#pragma unroll
      for (int kk = 0; kk < 12; ++kk) {
#pragma unroll
        for (int nt = 0; nt < 4; ++nt) {
          int n = ngrp * 64 + nt * 16 + ln16;
          short8 w = *(const short8*)(WcB + (((size_t)(n * 12 + kk) * 4 + qp) * 8));
          acc[nt] = __builtin_amdgcn_mfma_f32_16x16x32_bf16(aF[kk], w, acc[nt], 0, 0, 0);
        }
      }
      const int g = ngrp >> 2;                     // gate 0:r 1:u 2:h
#pragma unroll
      for (int p = 0; p < 2; ++p) {                // nt pair (2p, 2p+1)
        int wvc = (ngrp & 3) * 2 + p;              // consuming rnn wave
#pragma unroll
        for (int r = 0; r < 4; ++r) {
          unsigned lo = (unsigned)(unsigned short)f2bf(acc[2 * p][r]);
          unsigned hi = (unsigned)(unsigned short)f2bf(acc[2 * p + 1][r]);
          slab[g * 512 + wvc * 64 + r * 16 + ln16] = lo | (hi << 16);
        }
      }
    }

    __syncthreads();                               // all 512 threads' stores done
    if (tid == 0) {
      __threadfence();                             // L2 writeback: cross-XCD visible
      __hip_atomic_store(&flags[(2 * tpair) * 8 + mt], 1,
                         __ATOMIC_RELEASE, __HIP_MEMORY_SCOPE_AGENT);
      __hip_atomic_store(&flags[(2 * tpair + 1) * 8 + mt], 1,
                         __ATOMIC_RELEASE, __HIP_MEMORY_SCOPE_AGENT);
    }
    return;
  }

  // =================== rnn role: persistent recurrence ===================
  short* hFc = smem;                    // h,  rows 0..3 compact (4*HSTRIDE)
  short* rFc = smem + 4 * HSTRIDE;      // r*h

  const int tid = threadIdx.x;
  const int wv = tid >> 6, lane = tid & 63, ln16 = lane & 15, q = lane >> 4;
  const int row4 = lane & 3;            // A-frag source row (m & 3)
  const int wg = blockIdx.x;
  const int mtg = wg >> 2;              // producer mt group

  // persistent weight fragments: this wave's 32 cols of each gate
  short8 wR[2][8], wU[2][8], wH[2][8];
#pragma unroll
  for (int nt = 0; nt < 2; ++nt) {
    int nr = wv * 32 + nt * 16 + ln16;
#pragma unroll
    for (int kk = 0; kk < 8; ++kk) {
      wR[nt][kk] = *(const short8*)(WhB + (((size_t)(nr * 8 + kk) * 4 + q) * 8));
      wU[nt][kk] = *(const short8*)(WhB + (((size_t)((256 + nr) * 8 + kk) * 4 + q) * 8));
      wH[nt][kk] = *(const short8*)(WhB + (((size_t)((512 + nr) * 8 + kk) * 4 + q) * 8));
    }
  }
  for (int i = tid; i < 4 * HSTRIDE; i += 512) { hFc[i] = 0; rFc[i] = 0; }

  const floatx4 z4 = {0.f, 0.f, 0.f, 0.f};
  float hq[2] = {0.f, 0.f};             // h(row=q, col = wv*32 + nt*16 + ln16)

  const unsigned* slab0 = pre2 + (size_t)wg * SEQL * 1536;

  acq_spin(&flags[0 * 8 + mtg]);        // wait for slab 0
  unsigned cur0 = slab0[0 * 512 + tid];
  unsigned cur1 = slab0[1 * 512 + tid];
  unsigned cur2 = slab0[2 * 512 + tid];
  int fcur = __hip_atomic_load(&flags[1 * 8 + mtg],
                               __ATOMIC_RELAXED, __HIP_MEMORY_SCOPE_AGENT);

  float* outBase = out + ((size_t)(wg * 4 + q) * SEQL) * UNITS + wv * 32 + ln16;
  const int aoff = row4 * HSTRIDE + q * 8;       // + kk*32 per step
  const int woff = q * HSTRIDE + wv * 32 + ln16; // + nt*16

  __syncthreads();

  for (int t = 0; t < SEQL; ++t) {
    // issue next-next flag read now; its result is needed only next iter
    int fnxt = 1;
    if (t + 2 < SEQL)
      fnxt = __hip_atomic_load(&flags[(t + 2) * 8 + mtg],
                               __ATOMIC_RELAXED, __HIP_MEMORY_SCOPE_AGENT);
    // gate for slab t+1 (value pipelined from last iteration; spin = rare)
    if (t + 1 < SEQL && fcur == 0) acq_spin(&flags[(t + 1) * 8 + mtg]);
    asm volatile("" ::: "memory");      // keep prefetch below the gate

    const unsigned* nslab = slab0 + (size_t)(t < SEQL - 1 ? t + 1 : t) * 1536;
    unsigned nxt0 = nslab[0 * 512 + tid];
    unsigned nxt1 = nslab[1 * 512 + tid];
    unsigned nxt2 = nslab[2 * 512 + tid];

    // ---- phase A: r,u pre-acts ----
    floatx4 accR[2], accU[2];
    {
      const short8 a0 = *(const short8*)&hFc[aoff];
      accR[0] = __builtin_amdgcn_mfma_f32_16x16x32_bf16(a0, wR[0][0], z4, 0, 0, 0);
      accR[1] = __builtin_amdgcn_mfma_f32_16x16x32_bf16(a0, wR[1][0], z4, 0, 0, 0);
      accU[0] = __builtin_amdgcn_mfma_f32_16x16x32_bf16(a0, wU[0][0], z4, 0, 0, 0);
      accU[1] = __builtin_amdgcn_mfma_f32_16x16x32_bf16(a0, wU[1][0], z4, 0, 0, 0);
    }
#pragma unroll
    for (int kk = 1; kk < 8; ++kk) {
      const short8 a = *(const short8*)&hFc[aoff + kk * 32];
      accR[0] = __builtin_amdgcn_mfma_f32_16x16x32_bf16(a, wR[0][kk], accR[0], 0, 0, 0);
      accR[1] = __builtin_amdgcn_mfma_f32_16x16x32_bf16(a, wR[1][kk], accR[1], 0, 0, 0);
      accU[0] = __builtin_amdgcn_mfma_f32_16x16x32_bf16(a, wU[0][kk], accU[0], 0, 0, 0);
      accU[1] = __builtin_amdgcn_mfma_f32_16x16x32_bf16(a, wU[1][kk], accU[1], 0, 0, 0);
    }
    float uq[2];
#pragma unroll
    for (int nt = 0; nt < 2; ++nt) {
      float vR = (q == 0) ? accR[nt][0] : (q == 1) ? accR[nt][1]
               : (q == 2) ? accR[nt][2] : accR[nt][3];
      float vU = (q == 0) ? accU[nt][0] : (q == 1) ? accU[nt][1]
               : (q == 2) ? accU[nt][2] : accU[nt][3];
      float pR = bf2f((unsigned short)(nt ? (cur0 >> 16) : (cur0 & 0xffff)));
      float pU = bf2f((unsigned short)(nt ? (cur1 >> 16) : (cur1 & 0xffff)));
      float rg = frcp(1.f + fexp2(vR + pR));
      uq[nt]   = frcp(1.f + fexp2(vU + pU));
      rFc[woff + nt * 16] = f2bf(rg * hq[nt]);
    }
    LDS_BARRIER();

    // ---- phase B: cand, h update ----
    floatx4 accH[2];
    {
      const short8 a0 = *(const short8*)&rFc[aoff];
      accH[0] = __builtin_amdgcn_mfma_f32_16x16x32_bf16(a0, wH[0][0], z4, 0, 0, 0);
      accH[1] = __builtin_amdgcn_mfma_f32_16x16x32_bf16(a0, wH[1][0], z4, 0, 0, 0);
    }
#pragma unroll
    for (int kk = 1; kk < 8; ++kk) {
      const short8 a = *(const short8*)&rFc[aoff + kk * 32];
      accH[0] = __builtin_amdgcn_mfma_f32_16x16x32_bf16(a, wH[0][kk], accH[0], 0, 0, 0);
      accH[1] = __builtin_amdgcn_mfma_f32_16x16x32_bf16(a, wH[1][kk], accH[1], 0, 0, 0);
    }
#pragma unroll
    for (int nt = 0; nt < 2; ++nt) {
      float vH = (q == 0) ? accH[nt][0] : (q == 1) ? accH[nt][1]
               : (q == 2) ? accH[nt][2] : accH[nt][3];
      float pH = bf2f((unsigned short)(nt ? (cur2 >> 16) : (cur2 & 0xffff)));
      float cand = 1.f - 2.f * frcp(1.f + fexp2(vH + pH));   // tanh (scale folded)
      float hnew = uq[nt] * (hq[nt] - cand) + cand;
      hq[nt] = hnew;
      hFc[woff + nt * 16] = f2bf(hnew);
      outBase[(size_t)t * UNITS + nt * 16] = hnew;
    }
    cur0 = nxt0; cur1 = nxt1; cur2 = nxt2; fcur = fnxt;
    LDS_BARRIER();
  }
}

extern "C" void kernel_launch(void* const* d_in, const int* in_sizes, int n_in,
                              void* d_out, int out_size, void* d_ws, size_t ws_size,
                              hipStream_t stream) {
  const float* x    = (const float*)d_in[0];
  const float* iw   = (const float*)d_in[1];
  const float* hw   = (const float*)d_in[2];
  const float* bias = (const float*)d_in[3];
  // d_in[4] (constant) is [I;0] — folded analytically, unused.
  float* out = (float*)d_out;

  unsigned* pre2 = (unsigned*)d_ws;                    // 32*1024*1536 dwords = 192 MB
  const size_t preDwords = (size_t)32 * SEQL * 1536;
  short* WcB = (short*)(pre2 + preDwords);             // 384*768 bf16
  short* WhB = WcB + (size_t)384 * G3;                 // 256*768 bf16
  int* flags = (int*)(WhB + (size_t)256 * G3);         // 8192 ints

  prep_kernel<<<1952, 256, 0, stream>>>(iw, hw, WcB, WhB, flags);
  fused_kernel<<<32 + 4096, 512, 0, stream>>>(x, WcB, bias, pre2, WhB, out, flags);
}

// Round 5
// 1573.070 us; speedup vs baseline: 3.3440x; 1.0004x over previous
//
#include <hip/hip_runtime.h>

#define SEQL 1024
#define BATCHN 128
#define UNITS 256
#define INDIM 128
#define G3 768   // r|u|h gate columns

typedef __attribute__((ext_vector_type(8))) short short8;
typedef __attribute__((ext_vector_type(4))) short short4v;
typedef __attribute__((ext_vector_type(4))) float floatx4;

#define NL2E  -1.4426950408889634f   // -log2(e): r,u gate scale
#define PL2E2  2.8853900817779268f   //  2*log2(e): h gate scale

#define HSTRIDE 272                  // compact h row stride (shorts), breaks bank alias

__device__ __forceinline__ short f2bf(float f) {
  unsigned u = __float_as_uint(f);
  u += 0x7fff + ((u >> 16) & 1);   // round-to-nearest-even
  return (short)(u >> 16);
}
__device__ __forceinline__ float bf2f(unsigned short s) {
  return __uint_as_float(((unsigned)s) << 16);
}
__device__ __forceinline__ float fexp2(float x) {
#if __has_builtin(__builtin_amdgcn_exp2f)
  return __builtin_amdgcn_exp2f(x);
#else
  return __expf(0.6931471805599453f * x);
#endif
}
__device__ __forceinline__ float frcp(float x) {
#if __has_builtin(__builtin_amdgcn_rcpf)
  return __builtin_amdgcn_rcpf(x);
#else
  return 1.f / x;
#endif
}

// LDS-only barrier: orders ds ops without draining vmcnt.
#define LDS_BARRIER() do {                                   \
    asm volatile("s_waitcnt lgkmcnt(0)" ::: "memory");       \
    __builtin_amdgcn_s_barrier();                            \
    asm volatile("" ::: "memory");                           \
  } while (0)

// Acquire-spin on a producer flag. Acquire semantics invalidate stale L2
// lines each poll, so progress is guaranteed even if a relaxed fast-path
// read saw a stale 0.
__device__ __forceinline__ void acq_spin(const int* p) {
  while (__hip_atomic_load(p, __ATOMIC_ACQUIRE, __HIP_MEMORY_SCOPE_AGENT) == 0)
    __builtin_amdgcn_s_sleep(8);
}

// ---------------------------------------------------------------------------
// Kernel A: weight prep (unchanged math) + zeroing the 8192 producer flags.
// Grid 1952x256 = 294912 (WcB) + 196608 (WhB) + 8192 (flags) exactly.
// ---------------------------------------------------------------------------
__global__ void prep_kernel(const float* __restrict__ iw,   // (128,1792)
                            const float* __restrict__ hw,   // (256,768)
                            short* __restrict__ WcB, short* __restrict__ WhB,
                            int* __restrict__ flags) {
  int idx = blockIdx.x * 256 + threadIdx.x;
  const int WCN = 384 * G3;
  if (idx < WCN) {
    int k = idx / G3, n = idx % G3;
    int i = k & 127, blkk = k >> 7;      // 0:x_t 1:x_{t-1} 2:x_{t-2}
    int gsel = n >> 8, c = n & 255;      // 0:r 1:u 2:h
    const float* row = iw + (size_t)i * 1792;
    float v;
    if (blkk == 0) {
      v = (gsel == 0) ? row[c] + row[768 + c] + row[1280 + c]
        : (gsel == 1) ? row[256 + c] + row[1024 + c] + row[1536 + c]
                      : row[512 + c];
    } else if (blkk == 1) {
      v = (gsel == 0) ? -(row[768 + c] + 2.f * row[1280 + c])
        : (gsel == 1) ? -(row[1024 + c] + 2.f * row[1536 + c])
                      : 0.f;
    } else {
      v = (gsel == 0) ? row[1280 + c]
        : (gsel == 1) ? row[1536 + c]
                      : 0.f;
    }
    v *= (gsel == 2) ? PL2E2 : NL2E;
    int kk = k >> 5, q = (k >> 3) & 3, j = k & 7;
    WcB[(((n * 12 + kk) * 4 + q) * 8) + j] = f2bf(v);
  } else {
    idx -= WCN;
    if (idx < 256 * G3) {
      int k = idx / G3, n = idx % G3;
      float v = hw[(size_t)k * G3 + n] * ((n >> 8) == 2 ? PL2E2 : NL2E);
      int kk = k >> 5, q = (k >> 3) & 3, j = k & 7;
      WhB[(((n * 8 + kk) * 4 + q) * 8) + j] = f2bf(v);
    } else {
      idx -= 256 * G3;
      if (idx < SEQL * 8) flags[idx] = 0;
    }
  }
}

// ---------------------------------------------------------------------------
// Fused kernel: blocks 0..31 = persistent recurrence (consumer), blocks
// 32..4127 = input projection (producer), one proj block per (t-pair, mt).
// Handoff via flags[t*8+mt] (release store after threadfence; consumer
// pipelines the flag read one step ahead with an acquire-spin slow path).
// NEW (R5): rnn waves run at s_setprio(2) for their whole lifetime. With
// 2 blocks/CU, each rnn CU also hosts a proj block during the ~700us proj
// span; round-robin arbitration stole ~45% of issue slots from the
// latency-critical rnn chain (rnn 1157 standalone -> 1484 fused). Priority
// makes proj waves fill only rnn's stall cycles.
// ---------------------------------------------------------------------------
__global__ __launch_bounds__(512, 2) void fused_kernel(
    const float* __restrict__ x, const short* __restrict__ WcB,
    const float* __restrict__ bias, unsigned* __restrict__ pre2,
    const short* __restrict__ WhB, float* __restrict__ out,
    int* __restrict__ flags) {
  __shared__ __align__(16) short smem[12288];   // 24 KB: proj 2x6144, rnn 2176

  if (blockIdx.x >= 32) {
    // =================== proj role: (t-pair, mt) ===================
    const int pidx = blockIdx.x - 32;
    const int tpair = pidx >> 3, mt = pidx & 7;
    const int tid = threadIdx.x;
    const int half = tid >> 8, htid = tid & 255;
    const int t = tpair * 2 + half;
    short* xF = smem + half * 6144;             // [kk][lane][8] bf16 A-frags

#pragma unroll
    for (int it = 0; it < 6; ++it) {
      int rr = it * 8 + (htid >> 5);            // 0..47 = dt*16 + bb
      int dt = rr >> 4, bb = rr & 15;
      int lane32 = htid & 31, c = lane32 * 4;
      floatx4 v = {0.f, 0.f, 0.f, 0.f};
      if (t >= dt)
        v = *(const floatx4*)(x + ((size_t)(mt * 16 + bb) * SEQL + (t - dt)) * INDIM + c);
      int kk = dt * 4 + (c >> 5), qq = (c >> 3) & 3, j0 = c & 7;
      short4v pk;
#pragma unroll
      for (int j = 0; j < 4; ++j) pk[j] = f2bf(v[j]);
      *(short4v*)&xF[((kk * 64 + qq * 16 + bb) * 8) + j0] = pk;
    }
    __syncthreads();

    const int wvp = htid >> 6, lane = htid & 63, ln16 = lane & 15;
    const int qp = lane >> 4;

    short8 aF[12];
#pragma unroll
    for (int kk = 0; kk < 12; ++kk) aF[kk] = *(const short8*)&xF[(kk * 64 + lane) * 8];

    unsigned* slab = pre2 + (size_t)((mt * 4 + qp) * SEQL + t) * 1536;

#pragma unroll
    for (int ig = 0; ig < 3; ++ig) {
      const int ngrp = wvp * 3 + ig;               // 0..11 -> 64-col group
      const float sc = (ngrp >= 8) ? PL2E2 : NL2E;
      floatx4 acc[4];
#pragma unroll
      for (int nt = 0; nt < 4; ++nt) {
        float bv = bias[ngrp * 64 + nt * 16 + ln16] * sc;
#pragma unroll
        for (int r = 0; r < 4; ++r) acc[nt][r] = bv;
      }
#pragma unroll
      for (int kk = 0; kk < 12; ++kk) {
#pragma unroll
        for (int nt = 0; nt < 4; ++nt) {
          int n = ngrp * 64 + nt * 16 + ln16;
          short8 w = *(const short8*)(WcB + (((size_t)(n * 12 + kk) * 4 + qp) * 8));
          acc[nt] = __builtin_amdgcn_mfma_f32_16x16x32_bf16(aF[kk], w, acc[nt], 0, 0, 0);
        }
      }
      const int g = ngrp >> 2;                     // gate 0:r 1:u 2:h
#pragma unroll
      for (int p = 0; p < 2; ++p) {                // nt pair (2p, 2p+1)
        int wvc = (ngrp & 3) * 2 + p;              // consuming rnn wave
#pragma unroll
        for (int r = 0; r < 4; ++r) {
          unsigned lo = (unsigned)(unsigned short)f2bf(acc[2 * p][r]);
          unsigned hi = (unsigned)(unsigned short)f2bf(acc[2 * p + 1][r]);
          slab[g * 512 + wvc * 64 + r * 16 + ln16] = lo | (hi << 16);
        }
      }
    }

    __syncthreads();                               // all 512 threads' stores done
    if (tid == 0) {
      __threadfence();                             // L2 writeback: cross-XCD visible
      __hip_atomic_store(&flags[(2 * tpair) * 8 + mt], 1,
                         __ATOMIC_RELEASE, __HIP_MEMORY_SCOPE_AGENT);
      __hip_atomic_store(&flags[(2 * tpair + 1) * 8 + mt], 1,
                         __ATOMIC_RELEASE, __HIP_MEMORY_SCOPE_AGENT);
    }
    return;
  }

  // =================== rnn role: persistent recurrence ===================
  __builtin_amdgcn_s_setprio(2);        // rnn waves win issue arbitration vs
                                        // co-resident proj waves (prio 0)

  short* hFc = smem;                    // h,  rows 0..3 compact (4*HSTRIDE)
  short* rFc = smem + 4 * HSTRIDE;      // r*h

  const int tid = threadIdx.x;
  const int wv = tid >> 6, lane = tid & 63, ln16 = lane & 15, q = lane >> 4;
  const int row4 = lane & 3;            // A-frag source row (m & 3)
  const int wg = blockIdx.x;
  const int mtg = wg >> 2;              // producer mt group

  // persistent weight fragments: this wave's 32 cols of each gate
  short8 wR[2][8], wU[2][8], wH[2][8];
#pragma unroll
  for (int nt = 0; nt < 2; ++nt) {
    int nr = wv * 32 + nt * 16 + ln16;
#pragma unroll
    for (int kk = 0; kk < 8; ++kk) {
      wR[nt][kk] = *(const short8*)(WhB + (((size_t)(nr * 8 + kk) * 4 + q) * 8));
      wU[nt][kk] = *(const short8*)(WhB + (((size_t)((256 + nr) * 8 + kk) * 4 + q) * 8));
      wH[nt][kk] = *(const short8*)(WhB + (((size_t)((512 + nr) * 8 + kk) * 4 + q) * 8));
    }
  }
  for (int i = tid; i < 4 * HSTRIDE; i += 512) { hFc[i] = 0; rFc[i] = 0; }

  const floatx4 z4 = {0.f, 0.f, 0.f, 0.f};
  float hq[2] = {0.f, 0.f};             // h(row=q, col = wv*32 + nt*16 + ln16)

  const unsigned* slab0 = pre2 + (size_t)wg * SEQL * 1536;

  acq_spin(&flags[0 * 8 + mtg]);        // wait for slab 0
  unsigned cur0 = slab0[0 * 512 + tid];
  unsigned cur1 = slab0[1 * 512 + tid];
  unsigned cur2 = slab0[2 * 512 + tid];
  int fcur = __hip_atomic_load(&flags[1 * 8 + mtg],
                               __ATOMIC_RELAXED, __HIP_MEMORY_SCOPE_AGENT);

  float* outBase = out + ((size_t)(wg * 4 + q) * SEQL) * UNITS + wv * 32 + ln16;
  const int aoff = row4 * HSTRIDE + q * 8;       // + kk*32 per step
  const int woff = q * HSTRIDE + wv * 32 + ln16; // + nt*16

  __syncthreads();

  for (int t = 0; t < SEQL; ++t) {
    // issue next-next flag read now; its result is needed only next iter
    int fnxt = 1;
    if (t + 2 < SEQL)
      fnxt = __hip_atomic_load(&flags[(t + 2) * 8 + mtg],
                               __ATOMIC_RELAXED, __HIP_MEMORY_SCOPE_AGENT);
    // gate for slab t+1 (value pipelined from last iteration; spin = rare)
    if (t + 1 < SEQL && fcur == 0) acq_spin(&flags[(t + 1) * 8 + mtg]);
    asm volatile("" ::: "memory");      // keep prefetch below the gate

    const unsigned* nslab = slab0 + (size_t)(t < SEQL - 1 ? t + 1 : t) * 1536;
    unsigned nxt0 = nslab[0 * 512 + tid];
    unsigned nxt1 = nslab[1 * 512 + tid];
    unsigned nxt2 = nslab[2 * 512 + tid];

    // ---- phase A: r,u pre-acts ----
    floatx4 accR[2], accU[2];
    {
      const short8 a0 = *(const short8*)&hFc[aoff];
      accR[0] = __builtin_amdgcn_mfma_f32_16x16x32_bf16(a0, wR[0][0], z4, 0, 0, 0);
      accR[1] = __builtin_amdgcn_mfma_f32_16x16x32_bf16(a0, wR[1][0], z4, 0, 0, 0);
      accU[0] = __builtin_amdgcn_mfma_f32_16x16x32_bf16(a0, wU[0][0], z4, 0, 0, 0);
      accU[1] = __builtin_amdgcn_mfma_f32_16x16x32_bf16(a0, wU[1][0], z4, 0, 0, 0);
    }
#pragma unroll
    for (int kk = 1; kk < 8; ++kk) {
      const short8 a = *(const short8*)&hFc[aoff + kk * 32];
      accR[0] = __builtin_amdgcn_mfma_f32_16x16x32_bf16(a, wR[0][kk], accR[0], 0, 0, 0);
      accR[1] = __builtin_amdgcn_mfma_f32_16x16x32_bf16(a, wR[1][kk], accR[1], 0, 0, 0);
      accU[0] = __builtin_amdgcn_mfma_f32_16x16x32_bf16(a, wU[0][kk], accU[0], 0, 0, 0);
      accU[1] = __builtin_amdgcn_mfma_f32_16x16x32_bf16(a, wU[1][kk], accU[1], 0, 0, 0);
    }
    float uq[2];
#pragma unroll
    for (int nt = 0; nt < 2; ++nt) {
      float vR = (q == 0) ? accR[nt][0] : (q == 1) ? accR[nt][1]
               : (q == 2) ? accR[nt][2] : accR[nt][3];
      float vU = (q == 0) ? accU[nt][0] : (q == 1) ? accU[nt][1]
               : (q == 2) ? accU[nt][2] : accU[nt][3];
      float pR = bf2f((unsigned short)(nt ? (cur0 >> 16) : (cur0 & 0xffff)));
      float pU = bf2f((unsigned short)(nt ? (cur1 >> 16) : (cur1 & 0xffff)));
      float rg = frcp(1.f + fexp2(vR + pR));
      uq[nt]   = frcp(1.f + fexp2(vU + pU));
      rFc[woff + nt * 16] = f2bf(rg * hq[nt]);
    }
    LDS_BARRIER();

    // ---- phase B: cand, h update ----
    floatx4 accH[2];
    {
      const short8 a0 = *(const short8*)&rFc[aoff];
      accH[0] = __builtin_amdgcn_mfma_f32_16x16x32_bf16(a0, wH[0][0], z4, 0, 0, 0);
      accH[1] = __builtin_amdgcn_mfma_f32_16x16x32_bf16(a0, wH[1][0], z4, 0, 0, 0);
    }
#pragma unroll
    for (int kk = 1; kk < 8; ++kk) {
      const short8 a = *(const short8*)&rFc[aoff + kk * 32];
      accH[0] = __builtin_amdgcn_mfma_f32_16x16x32_bf16(a, wH[0][kk], accH[0], 0, 0, 0);
      accH[1] = __builtin_amdgcn_mfma_f32_16x16x32_bf16(a, wH[1][kk], accH[1], 0, 0, 0);
    }
#pragma unroll
    for (int nt = 0; nt < 2; ++nt) {
      float vH = (q == 0) ? accH[nt][0] : (q == 1) ? accH[nt][1]
               : (q == 2) ? accH[nt][2] : accH[nt][3];
      float pH = bf2f((unsigned short)(nt ? (cur2 >> 16) : (cur2 & 0xffff)));
      float cand = 1.f - 2.f * frcp(1.f + fexp2(vH + pH));   // tanh (scale folded)
      float hnew = uq[nt] * (hq[nt] - cand) + cand;
      hq[nt] = hnew;
      hFc[woff + nt * 16] = f2bf(hnew);
      outBase[(size_t)t * UNITS + nt * 16] = hnew;
    }
    cur0 = nxt0; cur1 = nxt1; cur2 = nxt2; fcur = fnxt;
    LDS_BARRIER();
  }
}

extern "C" void kernel_launch(void* const* d_in, const int* in_sizes, int n_in,
                              void* d_out, int out_size, void* d_ws, size_t ws_size,
                              hipStream_t stream) {
  const float* x    = (const float*)d_in[0];
  const float* iw   = (const float*)d_in[1];
  const float* hw   = (const float*)d_in[2];
  const float* bias = (const float*)d_in[3];
  // d_in[4] (constant) is [I;0] — folded analytically, unused.
  float* out = (float*)d_out;

  unsigned* pre2 = (unsigned*)d_ws;                    // 32*1024*1536 dwords = 192 MB
  const size_t preDwords = (size_t)32 * SEQL * 1536;
  short* WcB = (short*)(pre2 + preDwords);             // 384*768 bf16
  short* WhB = WcB + (size_t)384 * G3;                 // 256*768 bf16
  int* flags = (int*)(WhB + (size_t)256 * G3);         // 8192 ints

  prep_kernel<<<1952, 256, 0, stream>>>(iw, hw, WcB, WhB, flags);
  fused_kernel<<<32 + 4096, 512, 0, stream>>>(x, WcB, bias, pre2, WhB, out, flags);
}